// Round 18
// baseline (771.876 us; speedup 1.0000x reference)
//
#include <hip/hip_runtime.h>
#include <hip/hip_bf16.h>

#define NEMB 16

typedef short s16x8 __attribute__((ext_vector_type(8)));
typedef float f32x16 __attribute__((ext_vector_type(16)));
typedef unsigned int u32x8 __attribute__((ext_vector_type(8)));

__device__ __forceinline__ unsigned int pack_bf16x2_rnd(float lo, float hi) {
    unsigned int ul = __float_as_uint(lo);
    unsigned int uh = __float_as_uint(hi);
    return ((ul + 0x8000u) >> 16) | ((uh + 0x8000u) & 0xffff0000u);
}
// truncate-pack [bf16(lo), bf16(hi)] into one u32 with a single v_perm
__device__ __forceinline__ unsigned int pack_bf16x2_trunc(float lo, float hi) {
    return __builtin_amdgcn_perm(__float_as_uint(hi), __float_as_uint(lo),
                                 0x07060302u);
}

// ---------------------------------------------------------------------------
// Kernel P: emb f32 -> bf16 table (3.2 MB, L2-resident). 8 floats/thread.
// ---------------------------------------------------------------------------
__global__ __launch_bounds__(256) void emb_to_bf16_kernel(
        const float* __restrict__ emb, unsigned int* __restrict__ embT,
        int nWords) {  // nWords = nNodes*8 (one word = 2 bf16)
    int i = (blockIdx.x * 256 + threadIdx.x) * 4;
    if (i + 4 <= nWords) {
        float4 a = *reinterpret_cast<const float4*>(emb + 2 * i);
        float4 b = *reinterpret_cast<const float4*>(emb + 2 * i + 4);
        uint4 r;
        r.x = pack_bf16x2_rnd(a.x, a.y);
        r.y = pack_bf16x2_rnd(a.z, a.w);
        r.z = pack_bf16x2_rnd(b.x, b.y);
        r.w = pack_bf16x2_rnd(b.z, b.w);
        *reinterpret_cast<uint4*>(embT + i) = r;
    } else {
        for (; i < nWords; ++i)
            embT[i] = pack_bf16x2_rnd(emb[2 * i], emb[2 * i + 1]);
    }
}

// ---------------------------------------------------------------------------
// Shared frag-build macros (verified r5-r9):
//   32x32x16 MFMA, swapped operands. D col = lane&31 = edge; D row n(r) =
//   (r&3)+8*(r>>2)+4*(lane>>5).  permlane32_swap: vdst_hi <-> vsrc_lo;
//   B-frag exchange needs x_hi <-> y_lo  =>  vdst = x, vsrc = y.
// Constant vectors (b1/b2/w3) held PACKED bf16 (8 u32 each instead of 16 f32)
// to cut 32 persistent VGPRs; unpack-on-use temps are absorbed by MFMA C/D
// register reuse (D overwrites C).
// ---------------------------------------------------------------------------
#define WAVES 4
#define ITERS 8
#define EDGES_PER_BLOCK (WAVES * 32 * ITERS)   // 1024

#define MAKE_FRAG(BF, AT, M)                                                   \
    {                                                                          \
        unsigned int x0 = pack_bf16x2_trunc(fmaxf((AT)[8*(M)+0], 0.f),         \
                                            fmaxf((AT)[8*(M)+1], 0.f));        \
        unsigned int x1 = pack_bf16x2_trunc(fmaxf((AT)[8*(M)+2], 0.f),         \
                                            fmaxf((AT)[8*(M)+3], 0.f));        \
        unsigned int y0 = pack_bf16x2_trunc(fmaxf((AT)[8*(M)+4], 0.f),         \
                                            fmaxf((AT)[8*(M)+5], 0.f));        \
        unsigned int y1 = pack_bf16x2_trunc(fmaxf((AT)[8*(M)+6], 0.f),         \
                                            fmaxf((AT)[8*(M)+7], 0.f));        \
        asm("v_permlane32_swap_b32 %0, %1" : "+v"(x0), "+v"(y0));              \
        asm("v_permlane32_swap_b32 %0, %1" : "+v"(x1), "+v"(y1));              \
        BF.u[0] = x0; BF.u[1] = x1; BF.u[2] = y0; BF.u[3] = y1;                \
    }

#define UNPACK16(DST, P)                                                       \
    { _Pragma("unroll") for (int q = 0; q < 8; ++q) {                          \
        DST[2*q]   = __uint_as_float((P)[q] << 16);                            \
        DST[2*q+1] = __uint_as_float((P)[q] & 0xffff0000u); } }

#define LOAD_CONSTS                                                            \
    s16x8 A1_00, A1_01, A1_10, A1_11;                                          \
    {                                                                          \
        s16x8 a;                                                               \
        _Pragma("unroll") for (int i = 0; i < 8; ++i) {                        \
            float v = W1[(0 * 16 + hi * 8 + i) * 64 + 0 * 32 + el];            \
            a[i] = (short)((__float_as_uint(v) + 0x8000u) >> 16); }            \
        A1_00 = a;                                                             \
        _Pragma("unroll") for (int i = 0; i < 8; ++i) {                        \
            float v = W1[(1 * 16 + hi * 8 + i) * 64 + 0 * 32 + el];            \
            a[i] = (short)((__float_as_uint(v) + 0x8000u) >> 16); }            \
        A1_01 = a;                                                             \
        _Pragma("unroll") for (int i = 0; i < 8; ++i) {                        \
            float v = W1[(0 * 16 + hi * 8 + i) * 64 + 1 * 32 + el];            \
            a[i] = (short)((__float_as_uint(v) + 0x8000u) >> 16); }            \
        A1_10 = a;                                                             \
        _Pragma("unroll") for (int i = 0; i < 8; ++i) {                        \
            float v = W1[(1 * 16 + hi * 8 + i) * 64 + 1 * 32 + el];            \
            a[i] = (short)((__float_as_uint(v) + 0x8000u) >> 16); }            \
        A1_11 = a;                                                             \
    }                                                                          \
    s16x8 A2_0, A2_1, A2_2, A2_3;                                              \
    {                                                                          \
        s16x8 a;                                                               \
        _Pragma("unroll") for (int i = 0; i < 8; ++i) {                        \
            float v = W2[(0 * 16 + hi * 8 + i) * 32 + el];                     \
            a[i] = (short)((__float_as_uint(v) + 0x8000u) >> 16); }            \
        A2_0 = a;                                                              \
        _Pragma("unroll") for (int i = 0; i < 8; ++i) {                        \
            float v = W2[(1 * 16 + hi * 8 + i) * 32 + el];                     \
            a[i] = (short)((__float_as_uint(v) + 0x8000u) >> 16); }            \
        A2_1 = a;                                                              \
        _Pragma("unroll") for (int i = 0; i < 8; ++i) {                        \
            float v = W2[(2 * 16 + hi * 8 + i) * 32 + el];                     \
            a[i] = (short)((__float_as_uint(v) + 0x8000u) >> 16); }            \
        A2_2 = a;                                                              \
        _Pragma("unroll") for (int i = 0; i < 8; ++i) {                        \
            float v = W2[(3 * 16 + hi * 8 + i) * 32 + el];                     \
            a[i] = (short)((__float_as_uint(v) + 0x8000u) >> 16); }            \
        A2_3 = a;                                                              \
    }                                                                          \
    u32x8 b1p0, b1p1, b2p, w3p;                                                \
    _Pragma("unroll") for (int q = 0; q < 8; ++q) {                            \
        int r0 = 2 * q;                                                        \
        int n0 = (r0 & 3) + 8 * (r0 >> 2) + 4 * hi;                            \
        int n1 = n0 + 1;                                                       \
        b1p0[q] = pack_bf16x2_rnd(b1[n0], b1[n1]);                             \
        b1p1[q] = pack_bf16x2_rnd(b1[32 + n0], b1[32 + n1]);                   \
        b2p[q]  = pack_bf16x2_rnd(b2[n0], b2[n1]);                             \
        w3p[q]  = pack_bf16x2_rnd(W3[n0], W3[n1]);                             \
    }                                                                          \
    const float b3v = b3[0];

#define TILE_BODY(ESQ, EDQ, VOUT)                                              \
    {                                                                          \
        union { uint4 q; s16x8 v; } es_, ed_;                                  \
        es_.q = (ESQ); ed_.q = (EDQ);                                          \
        f32x16 a0; UNPACK16(a0, b1p0)                                          \
        a0 = __builtin_amdgcn_mfma_f32_32x32x16_bf16(A1_00, es_.v, a0, 0, 0, 0); \
        a0 = __builtin_amdgcn_mfma_f32_32x32x16_bf16(A1_01, ed_.v, a0, 0, 0, 0); \
        f32x16 a1; UNPACK16(a1, b1p1)                                          \
        a1 = __builtin_amdgcn_mfma_f32_32x32x16_bf16(A1_10, es_.v, a1, 0, 0, 0); \
        a1 = __builtin_amdgcn_mfma_f32_32x32x16_bf16(A1_11, ed_.v, a1, 0, 0, 0); \
        union { unsigned int u[4]; s16x8 v; } bf0, bf1, bf2, bf3;              \
        MAKE_FRAG(bf0, a0, 0)                                                  \
        MAKE_FRAG(bf1, a0, 1)                                                  \
        MAKE_FRAG(bf2, a1, 0)                                                  \
        MAKE_FRAG(bf3, a1, 1)                                                  \
        f32x16 acc; UNPACK16(acc, b2p)                                         \
        acc = __builtin_amdgcn_mfma_f32_32x32x16_bf16(A2_0, bf0.v, acc, 0, 0, 0); \
        acc = __builtin_amdgcn_mfma_f32_32x32x16_bf16(A2_1, bf1.v, acc, 0, 0, 0); \
        acc = __builtin_amdgcn_mfma_f32_32x32x16_bf16(A2_2, bf2.v, acc, 0, 0, 0); \
        acc = __builtin_amdgcn_mfma_f32_32x32x16_bf16(A2_3, bf3.v, acc, 0, 0, 0); \
        float pr[16];                                                          \
        _Pragma("unroll") for (int q = 0; q < 8; ++q) {                        \
            pr[2*q]   = fmaxf(acc[2*q],   0.0f) *                              \
                        __uint_as_float(w3p[q] << 16);                         \
            pr[2*q+1] = fmaxf(acc[2*q+1], 0.0f) *                              \
                        __uint_as_float(w3p[q] & 0xffff0000u);                 \
        }                                                                      \
        float s8[8];                                                           \
        _Pragma("unroll") for (int r = 0; r < 8; ++r)                          \
            s8[r] = pr[2 * r] + pr[2 * r + 1];                                 \
        float s4[4];                                                           \
        _Pragma("unroll") for (int r = 0; r < 4; ++r)                          \
            s4[r] = s8[2 * r] + s8[2 * r + 1];                                 \
        float vv = (s4[0] + s4[1]) + (s4[2] + s4[3]);                          \
        {                                                                      \
            float va = vv, vb = vv;                                            \
            asm("v_permlane32_swap_b32 %0, %1" : "+v"(vb), "+v"(va));          \
            vv = va + vb;                                                      \
        }                                                                      \
        VOUT = vv;                                                             \
    }

// ---------------------------------------------------------------------------
// Main kernel: full blocks only. Packed constants + early idx stores cut
// live VGPRs; __launch_bounds__(256,5) targets the 5-wave/SIMD band (<=102).
// ---------------------------------------------------------------------------
__global__ __launch_bounds__(256, 5) void edge_fused10_kernel(
        const unsigned short* __restrict__ embT,
        const int* __restrict__ ei,
        const float* __restrict__ W1, const float* __restrict__ b1,
        const float* __restrict__ W2, const float* __restrict__ b2,
        const float* __restrict__ W3, const float* __restrict__ b3,
        float* __restrict__ out, int nE) {
    const int tid = threadIdx.x;
    const int w  = tid >> 6;
    const int l  = tid & 63;
    const int el = l & 31;
    const int hi = l >> 5;

    LOAD_CONSTS

    const int base0 = blockIdx.x * EDGES_PER_BLOCK + w * 32;

    // prologue: all ei loads (coalesced, guard-free) + EARLY idx stores
    // (frees sv/dv liveness past their last gather use)
    int sv[ITERS], dv[ITERS];
#pragma unroll
    for (int i = 0; i < ITERS; ++i) {
        int e = base0 + i * (WAVES * 32) + el;
        sv[i] = ei[e];
        dv[i] = ei[nE + e];
    }
    if (hi == 0) {
#pragma unroll
        for (int i = 0; i < ITERS; ++i)
            out[nE + base0 + i * (WAVES * 32) + el] = (float)sv[i];
    } else {
#pragma unroll
        for (int i = 0; i < ITERS; ++i)
            out[(size_t)2 * nE + base0 + i * (WAVES * 32) + el] = (float)dv[i];
    }

    auto GATHER = [&](int s, int d, uint4& es, uint4& ed) {
        es = *reinterpret_cast<const uint4*>(embT + ((size_t)s << 4) + (hi << 3));
        ed = *reinterpret_cast<const uint4*>(embT + ((size_t)d << 4) + (hi << 3));
    };

    float lg[ITERS];
    uint4 esA, edA, esB, edB;
    GATHER(sv[0], dv[0], esA, edA);
#pragma unroll
    for (int it = 0; it < ITERS; it += 2) {
        if (it + 1 < ITERS) GATHER(sv[it + 1], dv[it + 1], esB, edB);
        TILE_BODY(esA, edA, lg[it])
        if (it + 2 < ITERS) GATHER(sv[it + 2], dv[it + 2], esA, edA);
        if (it + 1 < ITERS) TILE_BODY(esB, edB, lg[it + 1])
    }

    // batched prob epilogue (idx already stored)
    if (hi == 0) {
#pragma unroll
        for (int it = 0; it < ITERS; ++it) {
            int e = base0 + it * (WAVES * 32) + el;
            out[e] = 1.0f / (1.0f + __expf(-(lg[it] + b3v)));
        }
    }
}

// ---------------------------------------------------------------------------
// Guarded remainder kernel (edges [eStart, nE)).
// ---------------------------------------------------------------------------
__global__ __launch_bounds__(256) void edge_guard_kernel(
        const unsigned short* __restrict__ embT,
        const int* __restrict__ ei,
        const float* __restrict__ W1, const float* __restrict__ b1,
        const float* __restrict__ W2, const float* __restrict__ b2,
        const float* __restrict__ W3, const float* __restrict__ b3,
        float* __restrict__ out, int nE, int eStart) {
    const int tid = threadIdx.x;
    const int w  = tid >> 6;
    const int l  = tid & 63;
    const int el = l & 31;
    const int hi = l >> 5;

    LOAD_CONSTS

    const int base0 = eStart + blockIdx.x * EDGES_PER_BLOCK + w * 32;

    int sv[ITERS], dv[ITERS];
#pragma unroll
    for (int i = 0; i < ITERS; ++i) {
        int e  = base0 + i * (WAVES * 32) + el;
        int ec = e < nE ? e : (nE - 1);
        sv[i] = ei[ec];
        dv[i] = ei[nE + ec];
    }

    auto GATHER = [&](int s, int d, uint4& es, uint4& ed) {
        es = *reinterpret_cast<const uint4*>(embT + ((size_t)s << 4) + (hi << 3));
        ed = *reinterpret_cast<const uint4*>(embT + ((size_t)d << 4) + (hi << 3));
    };
    auto DO_TILE = [&](uint4 esq, uint4 edq, int it, int s, int d) {
        float vv;
        TILE_BODY(esq, edq, vv)
        float p = 1.0f / (1.0f + __expf(-(vv + b3v)));
        int e = base0 + it * (WAVES * 32) + el;
        if (e < nE) {
            if (hi == 0) {
                out[e] = p;
                out[nE + e] = (float)s;
            } else {
                out[(size_t)2 * nE + e] = (float)d;
            }
        }
    };

    uint4 esA, edA, esB, edB;
    GATHER(sv[0], dv[0], esA, edA);
#pragma unroll
    for (int it = 0; it < ITERS; it += 2) {
        if (base0 + it * (WAVES * 32) >= nE) break;
        if (it + 1 < ITERS) GATHER(sv[it + 1], dv[it + 1], esB, edB);
        DO_TILE(esA, edA, it, sv[it], dv[it]);
        if (it + 2 < ITERS) GATHER(sv[it + 2], dv[it + 2], esA, edA);
        if (it + 1 < ITERS) DO_TILE(esB, edB, it + 1, sv[it + 1], dv[it + 1]);
    }
}

// ---------------------------------------------------------------------------
// Fallback: per-edge full MLP (no workspace), f32 output.
// ---------------------------------------------------------------------------
__global__ __launch_bounds__(256) void edge_mlp_naive_kernel(
        const float* __restrict__ emb, const int* __restrict__ ei,
        const float* __restrict__ W1, const float* __restrict__ b1,
        const float* __restrict__ W2, const float* __restrict__ b2,
        const float* __restrict__ W3, const float* __restrict__ b3,
        float* __restrict__ out, int nE) {
    __shared__ __align__(16) float sW1[32 * 64];
    __shared__ __align__(16) float sW2[64 * 32];
    __shared__ float sW3[32];
    __shared__ float sB1[64];
    __shared__ float sB2[32];
    __shared__ float sB3;
    for (int i = threadIdx.x; i < 2048; i += 256) {
        sW1[i] = W1[i];
        sW2[i] = W2[i];
    }
    if (threadIdx.x < 64) sB1[threadIdx.x] = b1[threadIdx.x];
    if (threadIdx.x < 32) {
        sW3[threadIdx.x] = W3[threadIdx.x];
        sB2[threadIdx.x] = b2[threadIdx.x];
    }
    if (threadIdx.x == 0) sB3 = b3[0];
    __syncthreads();

    int e = blockIdx.x * 256 + threadIdx.x;
    if (e >= nE) return;

    int s = ei[e];
    int d = ei[nE + e];

    float f[32];
    const float4* ps = reinterpret_cast<const float4*>(emb + (size_t)s * NEMB);
    const float4* pd = reinterpret_cast<const float4*>(emb + (size_t)d * NEMB);
#pragma unroll
    for (int q = 0; q < 4; ++q) {
        float4 v = ps[q];
        f[4 * q + 0] = v.x; f[4 * q + 1] = v.y; f[4 * q + 2] = v.z; f[4 * q + 3] = v.w;
    }
#pragma unroll
    for (int q = 0; q < 4; ++q) {
        float4 v = pd[q];
        f[16 + 4 * q + 0] = v.x; f[16 + 4 * q + 1] = v.y;
        f[16 + 4 * q + 2] = v.z; f[16 + 4 * q + 3] = v.w;
    }

    float h1[64];
#pragma unroll
    for (int j = 0; j < 64; j += 4) {
        float a0 = sB1[j + 0], a1 = sB1[j + 1], a2 = sB1[j + 2], a3 = sB1[j + 3];
#pragma unroll
        for (int k = 0; k < 32; ++k) {
            float4 wv = *reinterpret_cast<const float4*>(sW1 + k * 64 + j);
            a0 = fmaf(f[k], wv.x, a0);
            a1 = fmaf(f[k], wv.y, a1);
            a2 = fmaf(f[k], wv.z, a2);
            a3 = fmaf(f[k], wv.w, a3);
        }
        h1[j + 0] = fmaxf(a0, 0.0f);
        h1[j + 1] = fmaxf(a1, 0.0f);
        h1[j + 2] = fmaxf(a2, 0.0f);
        h1[j + 3] = fmaxf(a3, 0.0f);
    }

    float acc = sB3;
#pragma unroll
    for (int j = 0; j < 32; j += 4) {
        float a0 = sB2[j + 0], a1 = sB2[j + 1], a2 = sB2[j + 2], a3 = sB2[j + 3];
#pragma unroll
        for (int k = 0; k < 64; ++k) {
            float4 wv = *reinterpret_cast<const float4*>(sW2 + k * 32 + j);
            a0 = fmaf(h1[k], wv.x, a0);
            a1 = fmaf(h1[k], wv.y, a1);
            a2 = fmaf(h1[k], wv.z, a2);
            a3 = fmaf(h1[k], wv.w, a3);
        }
        acc = fmaf(fmaxf(a0, 0.0f), sW3[j + 0], acc);
        acc = fmaf(fmaxf(a1, 0.0f), sW3[j + 1], acc);
        acc = fmaf(fmaxf(a2, 0.0f), sW3[j + 2], acc);
        acc = fmaf(fmaxf(a3, 0.0f), sW3[j + 3], acc);
    }

    out[e] = 1.0f / (1.0f + __expf(-acc));
}

__global__ __launch_bounds__(256) void edge_idx_copy_kernel(
        const int* __restrict__ ei, float* __restrict__ out, int n) {
    int i = (blockIdx.x * 256 + threadIdx.x) * 4;
    if (i + 4 <= n) {
        int4 a = *reinterpret_cast<const int4*>(ei + i);
        float4 r = make_float4((float)a.x, (float)a.y, (float)a.z, (float)a.w);
        *reinterpret_cast<float4*>(out + i) = r;
    } else {
        for (; i < n; ++i) out[i] = (float)ei[i];
    }
}

extern "C" void kernel_launch(void* const* d_in, const int* in_sizes, int n_in,
                              void* d_out, int out_size, void* d_ws, size_t ws_size,
                              hipStream_t stream) {
    const float* emb = (const float*)d_in[0];
    const int*   ei  = (const int*)d_in[1];
    const float* W1  = (const float*)d_in[2];
    const float* b1  = (const float*)d_in[3];
    const float* W2  = (const float*)d_in[4];
    const float* b2  = (const float*)d_in[5];
    const float* W3  = (const float*)d_in[6];
    const float* b3  = (const float*)d_in[7];

    const int nNodes = in_sizes[0] / NEMB;   // 100000
    const int n2E    = in_sizes[1];          // 2 * E
    const int nE     = n2E / 2;              // E

    float* out = (float*)d_out;  // f32: [E probs][2E edge indices]

    const size_t tbl_bytes = (size_t)nNodes * NEMB * sizeof(unsigned short);  // 3.2 MB
    const bool use_ws = (ws_size >= tbl_bytes);

    if (use_ws) {
        unsigned int* embT = (unsigned int*)d_ws;
        const int nWords = nNodes * 8;
        emb_to_bf16_kernel<<<(nWords / 4 + 255) / 256, 256, 0, stream>>>(
            emb, embT, nWords);

        const int nFull = nE / EDGES_PER_BLOCK;
        if (nFull > 0) {
            edge_fused10_kernel<<<nFull, 256, 0, stream>>>(
                (const unsigned short*)embT, ei, W1, b1, W2, b2, W3, b3, out, nE);
        }
        const int rem = nE - nFull * EDGES_PER_BLOCK;   // 0 at E = 2^22
        if (rem > 0) {
            const int gBlocks = (rem + EDGES_PER_BLOCK - 1) / EDGES_PER_BLOCK;
            edge_guard_kernel<<<gBlocks, 256, 0, stream>>>(
                (const unsigned short*)embT, ei, W1, b1, W2, b2, W3, b3, out, nE,
                nFull * EDGES_PER_BLOCK);
        }
    } else {
        edge_mlp_naive_kernel<<<(nE + 255) / 256, 256, 0, stream>>>(
            emb, ei, W1, b1, W2, b2, W3, b3, out, nE);
        edge_idx_copy_kernel<<<((n2E + 3) / 4 + 255) / 256, 256, 0, stream>>>(
            ei, out + nE, n2E);
    }
}

// Round 19
// 78.799 us; speedup vs baseline: 9.7955x; 9.7955x over previous
//
#include <hip/hip_runtime.h>
#include <hip/hip_bf16.h>

#define NEMB 16

typedef short s16x8 __attribute__((ext_vector_type(8)));
typedef float f32x16 __attribute__((ext_vector_type(16)));

__device__ __forceinline__ unsigned int pack_bf16x2_rnd(float lo, float hi) {
    unsigned int ul = __float_as_uint(lo);
    unsigned int uh = __float_as_uint(hi);
    return ((ul + 0x8000u) >> 16) | ((uh + 0x8000u) & 0xffff0000u);
}
// truncate-pack [bf16(lo), bf16(hi)] into one u32 with a single v_perm
__device__ __forceinline__ unsigned int pack_bf16x2_trunc(float lo, float hi) {
    return __builtin_amdgcn_perm(__float_as_uint(hi), __float_as_uint(lo),
                                 0x07060302u);
}

// ---------------------------------------------------------------------------
// Kernel P: emb f32 -> bf16 table (3.2 MB, L2-resident). 8 floats/thread.
// ---------------------------------------------------------------------------
__global__ __launch_bounds__(256) void emb_to_bf16_kernel(
        const float* __restrict__ emb, unsigned int* __restrict__ embT,
        int nWords) {  // nWords = nNodes*8 (one word = 2 bf16)
    int i = (blockIdx.x * 256 + threadIdx.x) * 4;
    if (i + 4 <= nWords) {
        float4 a = *reinterpret_cast<const float4*>(emb + 2 * i);
        float4 b = *reinterpret_cast<const float4*>(emb + 2 * i + 4);
        uint4 r;
        r.x = pack_bf16x2_rnd(a.x, a.y);
        r.y = pack_bf16x2_rnd(a.z, a.w);
        r.z = pack_bf16x2_rnd(b.x, b.y);
        r.w = pack_bf16x2_rnd(b.z, b.w);
        *reinterpret_cast<uint4*>(embT + i) = r;
    } else {
        for (; i < nWords; ++i)
            embT[i] = pack_bf16x2_rnd(emb[2 * i], emb[2 * i + 1]);
    }
}

// ---------------------------------------------------------------------------
// Shared frag-build macros (verified r5-r9):
//   32x32x16 MFMA, swapped operands. D col = lane&31 = edge; D row n(r) =
//   (r&3)+8*(r>>2)+4*(lane>>5).  permlane32_swap: vdst_hi <-> vsrc_lo;
//   B-frag exchange needs x_hi <-> y_lo  =>  vdst = x, vsrc = y.
// ---------------------------------------------------------------------------
#define WAVES 4
#define ITERS 8
#define EDGES_PER_BLOCK (WAVES * 32 * ITERS)   // 1024

#define MAKE_FRAG(BF, AT, M)                                                   \
    {                                                                          \
        unsigned int x0 = pack_bf16x2_trunc(fmaxf((AT)[8*(M)+0], 0.f),         \
                                            fmaxf((AT)[8*(M)+1], 0.f));        \
        unsigned int x1 = pack_bf16x2_trunc(fmaxf((AT)[8*(M)+2], 0.f),         \
                                            fmaxf((AT)[8*(M)+3], 0.f));        \
        unsigned int y0 = pack_bf16x2_trunc(fmaxf((AT)[8*(M)+4], 0.f),         \
                                            fmaxf((AT)[8*(M)+5], 0.f));        \
        unsigned int y1 = pack_bf16x2_trunc(fmaxf((AT)[8*(M)+6], 0.f),         \
                                            fmaxf((AT)[8*(M)+7], 0.f));        \
        asm("v_permlane32_swap_b32 %0, %1" : "+v"(x0), "+v"(y0));              \
        asm("v_permlane32_swap_b32 %0, %1" : "+v"(x1), "+v"(y1));              \
        BF.u[0] = x0; BF.u[1] = x1; BF.u[2] = y0; BF.u[3] = y1;                \
    }

#define LOAD_CONSTS                                                            \
    s16x8 A1_00, A1_01, A1_10, A1_11;                                          \
    {                                                                          \
        s16x8 a;                                                               \
        _Pragma("unroll") for (int i = 0; i < 8; ++i) {                        \
            float v = W1[(0 * 16 + hi * 8 + i) * 64 + 0 * 32 + el];            \
            a[i] = (short)((__float_as_uint(v) + 0x8000u) >> 16); }            \
        A1_00 = a;                                                             \
        _Pragma("unroll") for (int i = 0; i < 8; ++i) {                        \
            float v = W1[(1 * 16 + hi * 8 + i) * 64 + 0 * 32 + el];            \
            a[i] = (short)((__float_as_uint(v) + 0x8000u) >> 16); }            \
        A1_01 = a;                                                             \
        _Pragma("unroll") for (int i = 0; i < 8; ++i) {                        \
            float v = W1[(0 * 16 + hi * 8 + i) * 64 + 1 * 32 + el];            \
            a[i] = (short)((__float_as_uint(v) + 0x8000u) >> 16); }            \
        A1_10 = a;                                                             \
        _Pragma("unroll") for (int i = 0; i < 8; ++i) {                        \
            float v = W1[(1 * 16 + hi * 8 + i) * 64 + 1 * 32 + el];            \
            a[i] = (short)((__float_as_uint(v) + 0x8000u) >> 16); }            \
        A1_11 = a;                                                             \
    }                                                                          \
    s16x8 A2_0, A2_1, A2_2, A2_3;                                              \
    {                                                                          \
        s16x8 a;                                                               \
        _Pragma("unroll") for (int i = 0; i < 8; ++i) {                        \
            float v = W2[(0 * 16 + hi * 8 + i) * 32 + el];                     \
            a[i] = (short)((__float_as_uint(v) + 0x8000u) >> 16); }            \
        A2_0 = a;                                                              \
        _Pragma("unroll") for (int i = 0; i < 8; ++i) {                        \
            float v = W2[(1 * 16 + hi * 8 + i) * 32 + el];                     \
            a[i] = (short)((__float_as_uint(v) + 0x8000u) >> 16); }            \
        A2_1 = a;                                                              \
        _Pragma("unroll") for (int i = 0; i < 8; ++i) {                        \
            float v = W2[(2 * 16 + hi * 8 + i) * 32 + el];                     \
            a[i] = (short)((__float_as_uint(v) + 0x8000u) >> 16); }            \
        A2_2 = a;                                                              \
        _Pragma("unroll") for (int i = 0; i < 8; ++i) {                        \
            float v = W2[(3 * 16 + hi * 8 + i) * 32 + el];                     \
            a[i] = (short)((__float_as_uint(v) + 0x8000u) >> 16); }            \
        A2_3 = a;                                                              \
    }                                                                          \
    f32x16 b1v0, b1v1, b2v;                                                    \
    float w3v[16];                                                             \
    _Pragma("unroll") for (int r = 0; r < 16; ++r) {                           \
        int n = (r & 3) + 8 * (r >> 2) + 4 * hi;                               \
        b1v0[r] = b1[n];                                                       \
        b1v1[r] = b1[32 + n];                                                  \
        b2v[r]  = b2[n];                                                       \
        w3v[r]  = W3[n];                                                       \
    }                                                                          \
    const float b3v = b3[0];

#define TILE_BODY(ESQ, EDQ, VOUT)                                              \
    {                                                                          \
        union { uint4 q; s16x8 v; } es_, ed_;                                  \
        es_.q = (ESQ); ed_.q = (EDQ);                                          \
        f32x16 a0 = __builtin_amdgcn_mfma_f32_32x32x16_bf16(A1_00, es_.v, b1v0, 0, 0, 0); \
        a0        = __builtin_amdgcn_mfma_f32_32x32x16_bf16(A1_01, ed_.v, a0,   0, 0, 0); \
        f32x16 a1 = __builtin_amdgcn_mfma_f32_32x32x16_bf16(A1_10, es_.v, b1v1, 0, 0, 0); \
        a1        = __builtin_amdgcn_mfma_f32_32x32x16_bf16(A1_11, ed_.v, a1,   0, 0, 0); \
        union { unsigned int u[4]; s16x8 v; } bf0, bf1, bf2, bf3;              \
        MAKE_FRAG(bf0, a0, 0)                                                  \
        MAKE_FRAG(bf1, a0, 1)                                                  \
        MAKE_FRAG(bf2, a1, 0)                                                  \
        MAKE_FRAG(bf3, a1, 1)                                                  \
        f32x16 acc;                                                            \
        acc = __builtin_amdgcn_mfma_f32_32x32x16_bf16(A2_0, bf0.v, b2v, 0, 0, 0); \
        acc = __builtin_amdgcn_mfma_f32_32x32x16_bf16(A2_1, bf1.v, acc, 0, 0, 0); \
        acc = __builtin_amdgcn_mfma_f32_32x32x16_bf16(A2_2, bf2.v, acc, 0, 0, 0); \
        acc = __builtin_amdgcn_mfma_f32_32x32x16_bf16(A2_3, bf3.v, acc, 0, 0, 0); \
        float pr[16];                                                          \
        _Pragma("unroll") for (int r = 0; r < 16; ++r)                         \
            pr[r] = fmaxf(acc[r], 0.0f) * w3v[r];                              \
        float s8[8];                                                           \
        _Pragma("unroll") for (int r = 0; r < 8; ++r)                          \
            s8[r] = pr[2 * r] + pr[2 * r + 1];                                 \
        float s4[4];                                                           \
        _Pragma("unroll") for (int r = 0; r < 4; ++r)                          \
            s4[r] = s8[2 * r] + s8[2 * r + 1];                                 \
        float vv = (s4[0] + s4[1]) + (s4[2] + s4[3]);                          \
        {                                                                      \
            float va = vv, vb = vv;                                            \
            asm("v_permlane32_swap_b32 %0, %1" : "+v"(vb), "+v"(va));          \
            vv = va + vb;                                                      \
        }                                                                      \
        VOUT = vv;                                                             \
    }

// ---------------------------------------------------------------------------
// Main kernel: full blocks only (no bounds checks). Logits held in registers;
// single batched sigmoid+store epilogue after the loop (one exec transition,
// sigmoid only in the hi=0 half, stores drain in parallel).
// ---------------------------------------------------------------------------
__global__ __launch_bounds__(256) void edge_fused7_kernel(
        const unsigned short* __restrict__ embT,
        const int* __restrict__ ei,
        const float* __restrict__ W1, const float* __restrict__ b1,
        const float* __restrict__ W2, const float* __restrict__ b2,
        const float* __restrict__ W3, const float* __restrict__ b3,
        float* __restrict__ out, int nE) {
    const int tid = threadIdx.x;
    const int w  = tid >> 6;
    const int l  = tid & 63;
    const int el = l & 31;
    const int hi = l >> 5;

    LOAD_CONSTS

    const int base0 = blockIdx.x * EDGES_PER_BLOCK + w * 32;

    // prologue: all ei loads (coalesced, guard-free — full blocks only)
    int sv[ITERS], dv[ITERS];
#pragma unroll
    for (int i = 0; i < ITERS; ++i) {
        int e = base0 + i * (WAVES * 32) + el;
        sv[i] = ei[e];
        dv[i] = ei[nE + e];
    }

    auto GATHER = [&](int s, int d, uint4& es, uint4& ed) {
        es = *reinterpret_cast<const uint4*>(embT + ((size_t)s << 4) + (hi << 3));
        ed = *reinterpret_cast<const uint4*>(embT + ((size_t)d << 4) + (hi << 3));
    };

    float lg[ITERS];
    uint4 esA, edA, esB, edB;
    GATHER(sv[0], dv[0], esA, edA);
#pragma unroll
    for (int it = 0; it < ITERS; it += 2) {
        if (it + 1 < ITERS) GATHER(sv[it + 1], dv[it + 1], esB, edB);
        TILE_BODY(esA, edA, lg[it])
        if (it + 2 < ITERS) GATHER(sv[it + 2], dv[it + 2], esA, edA);
        if (it + 1 < ITERS) TILE_BODY(esB, edB, lg[it + 1])
    }

    // batched epilogue: one exec-mask split, all stores together
    if (hi == 0) {
#pragma unroll
        for (int it = 0; it < ITERS; ++it) {
            int e = base0 + it * (WAVES * 32) + el;
            float p = 1.0f / (1.0f + __expf(-(lg[it] + b3v)));
            out[e] = p;                      // probs
            out[nE + e] = (float)sv[it];     // edge_index row 0
        }
    } else {
#pragma unroll
        for (int it = 0; it < ITERS; ++it) {
            int e = base0 + it * (WAVES * 32) + el;
            out[(size_t)2 * nE + e] = (float)dv[it];  // edge_index row 1
        }
    }
}

// ---------------------------------------------------------------------------
// Guarded remainder kernel (edges [eStart, nE)).
// ---------------------------------------------------------------------------
__global__ __launch_bounds__(256) void edge_guard_kernel(
        const unsigned short* __restrict__ embT,
        const int* __restrict__ ei,
        const float* __restrict__ W1, const float* __restrict__ b1,
        const float* __restrict__ W2, const float* __restrict__ b2,
        const float* __restrict__ W3, const float* __restrict__ b3,
        float* __restrict__ out, int nE, int eStart) {
    const int tid = threadIdx.x;
    const int w  = tid >> 6;
    const int l  = tid & 63;
    const int el = l & 31;
    const int hi = l >> 5;

    LOAD_CONSTS

    const int base0 = eStart + blockIdx.x * EDGES_PER_BLOCK + w * 32;

    int sv[ITERS], dv[ITERS];
#pragma unroll
    for (int i = 0; i < ITERS; ++i) {
        int e  = base0 + i * (WAVES * 32) + el;
        int ec = e < nE ? e : (nE - 1);
        sv[i] = ei[ec];
        dv[i] = ei[nE + ec];
    }

    auto GATHER = [&](int s, int d, uint4& es, uint4& ed) {
        es = *reinterpret_cast<const uint4*>(embT + ((size_t)s << 4) + (hi << 3));
        ed = *reinterpret_cast<const uint4*>(embT + ((size_t)d << 4) + (hi << 3));
    };
    auto DO_TILE = [&](uint4 esq, uint4 edq, int it, int s, int d) {
        float vv;
        TILE_BODY(esq, edq, vv)
        float p = 1.0f / (1.0f + __expf(-(vv + b3v)));
        int e = base0 + it * (WAVES * 32) + el;
        if (e < nE) {
            if (hi == 0) {
                out[e] = p;
                out[nE + e] = (float)s;
            } else {
                out[(size_t)2 * nE + e] = (float)d;
            }
        }
    };

    uint4 esA, edA, esB, edB;
    GATHER(sv[0], dv[0], esA, edA);
#pragma unroll
    for (int it = 0; it < ITERS; it += 2) {
        if (base0 + it * (WAVES * 32) >= nE) break;
        if (it + 1 < ITERS) GATHER(sv[it + 1], dv[it + 1], esB, edB);
        DO_TILE(esA, edA, it, sv[it], dv[it]);
        if (it + 2 < ITERS) GATHER(sv[it + 2], dv[it + 2], esA, edA);
        if (it + 1 < ITERS) DO_TILE(esB, edB, it + 1, sv[it + 1], dv[it + 1]);
    }
}

// ---------------------------------------------------------------------------
// Fallback: per-edge full MLP (no workspace), f32 output.
// ---------------------------------------------------------------------------
__global__ __launch_bounds__(256) void edge_mlp_naive_kernel(
        const float* __restrict__ emb, const int* __restrict__ ei,
        const float* __restrict__ W1, const float* __restrict__ b1,
        const float* __restrict__ W2, const float* __restrict__ b2,
        const float* __restrict__ W3, const float* __restrict__ b3,
        float* __restrict__ out, int nE) {
    __shared__ __align__(16) float sW1[32 * 64];
    __shared__ __align__(16) float sW2[64 * 32];
    __shared__ float sW3[32];
    __shared__ float sB1[64];
    __shared__ float sB2[32];
    __shared__ float sB3;
    for (int i = threadIdx.x; i < 2048; i += 256) {
        sW1[i] = W1[i];
        sW2[i] = W2[i];
    }
    if (threadIdx.x < 64) sB1[threadIdx.x] = b1[threadIdx.x];
    if (threadIdx.x < 32) {
        sW3[threadIdx.x] = W3[threadIdx.x];
        sB2[threadIdx.x] = b2[threadIdx.x];
    }
    if (threadIdx.x == 0) sB3 = b3[0];
    __syncthreads();

    int e = blockIdx.x * 256 + threadIdx.x;
    if (e >= nE) return;

    int s = ei[e];
    int d = ei[nE + e];

    float f[32];
    const float4* ps = reinterpret_cast<const float4*>(emb + (size_t)s * NEMB);
    const float4* pd = reinterpret_cast<const float4*>(emb + (size_t)d * NEMB);
#pragma unroll
    for (int q = 0; q < 4; ++q) {
        float4 v = ps[q];
        f[4 * q + 0] = v.x; f[4 * q + 1] = v.y; f[4 * q + 2] = v.z; f[4 * q + 3] = v.w;
    }
#pragma unroll
    for (int q = 0; q < 4; ++q) {
        float4 v = pd[q];
        f[16 + 4 * q + 0] = v.x; f[16 + 4 * q + 1] = v.y;
        f[16 + 4 * q + 2] = v.z; f[16 + 4 * q + 3] = v.w;
    }

    float h1[64];
#pragma unroll
    for (int j = 0; j < 64; j += 4) {
        float a0 = sB1[j + 0], a1 = sB1[j + 1], a2 = sB1[j + 2], a3 = sB1[j + 3];
#pragma unroll
        for (int k = 0; k < 32; ++k) {
            float4 wv = *reinterpret_cast<const float4*>(sW1 + k * 64 + j);
            a0 = fmaf(f[k], wv.x, a0);
            a1 = fmaf(f[k], wv.y, a1);
            a2 = fmaf(f[k], wv.z, a2);
            a3 = fmaf(f[k], wv.w, a3);
        }
        h1[j + 0] = fmaxf(a0, 0.0f);
        h1[j + 1] = fmaxf(a1, 0.0f);
        h1[j + 2] = fmaxf(a2, 0.0f);
        h1[j + 3] = fmaxf(a3, 0.0f);
    }

    float acc = sB3;
#pragma unroll
    for (int j = 0; j < 32; j += 4) {
        float a0 = sB2[j + 0], a1 = sB2[j + 1], a2 = sB2[j + 2], a3 = sB2[j + 3];
#pragma unroll
        for (int k = 0; k < 64; ++k) {
            float4 wv = *reinterpret_cast<const float4*>(sW2 + k * 32 + j);
            a0 = fmaf(h1[k], wv.x, a0);
            a1 = fmaf(h1[k], wv.y, a1);
            a2 = fmaf(h1[k], wv.z, a2);
            a3 = fmaf(h1[k], wv.w, a3);
        }
        acc = fmaf(fmaxf(a0, 0.0f), sW3[j + 0], acc);
        acc = fmaf(fmaxf(a1, 0.0f), sW3[j + 1], acc);
        acc = fmaf(fmaxf(a2, 0.0f), sW3[j + 2], acc);
        acc = fmaf(fmaxf(a3, 0.0f), sW3[j + 3], acc);
    }

    out[e] = 1.0f / (1.0f + __expf(-acc));
}

__global__ __launch_bounds__(256) void edge_idx_copy_kernel(
        const int* __restrict__ ei, float* __restrict__ out, int n) {
    int i = (blockIdx.x * 256 + threadIdx.x) * 4;
    if (i + 4 <= n) {
        int4 a = *reinterpret_cast<const int4*>(ei + i);
        float4 r = make_float4((float)a.x, (float)a.y, (float)a.z, (float)a.w);
        *reinterpret_cast<float4*>(out + i) = r;
    } else {
        for (; i < n; ++i) out[i] = (float)ei[i];
    }
}

extern "C" void kernel_launch(void* const* d_in, const int* in_sizes, int n_in,
                              void* d_out, int out_size, void* d_ws, size_t ws_size,
                              hipStream_t stream) {
    const float* emb = (const float*)d_in[0];
    const int*   ei  = (const int*)d_in[1];
    const float* W1  = (const float*)d_in[2];
    const float* b1  = (const float*)d_in[3];
    const float* W2  = (const float*)d_in[4];
    const float* b2  = (const float*)d_in[5];
    const float* W3  = (const float*)d_in[6];
    const float* b3  = (const float*)d_in[7];

    const int nNodes = in_sizes[0] / NEMB;   // 100000
    const int n2E    = in_sizes[1];          // 2 * E
    const int nE     = n2E / 2;              // E

    float* out = (float*)d_out;  // f32: [E probs][2E edge indices]

    const size_t tbl_bytes = (size_t)nNodes * NEMB * sizeof(unsigned short);  // 3.2 MB
    const bool use_ws = (ws_size >= tbl_bytes);

    if (use_ws) {
        unsigned int* embT = (unsigned int*)d_ws;
        const int nWords = nNodes * 8;
        emb_to_bf16_kernel<<<(nWords / 4 + 255) / 256, 256, 0, stream>>>(
            emb, embT, nWords);

        const int nFull = nE / EDGES_PER_BLOCK;
        if (nFull > 0) {
            edge_fused7_kernel<<<nFull, 256, 0, stream>>>(
                (const unsigned short*)embT, ei, W1, b1, W2, b2, W3, b3, out, nE);
        }
        const int rem = nE - nFull * EDGES_PER_BLOCK;   // 0 at E = 2^22
        if (rem > 0) {
            const int gBlocks = (rem + EDGES_PER_BLOCK - 1) / EDGES_PER_BLOCK;
            edge_guard_kernel<<<gBlocks, 256, 0, stream>>>(
                (const unsigned short*)embT, ei, W1, b1, W2, b2, W3, b3, out, nE,
                nFull * EDGES_PER_BLOCK);
        }
    } else {
        edge_mlp_naive_kernel<<<(nE + 255) / 256, 256, 0, stream>>>(
            emb, ei, W1, b1, W2, b2, W3, b3, out, nE);
        edge_idx_copy_kernel<<<((n2E + 3) / 4 + 255) / 256, 256, 0, stream>>>(
            ei, out + nE, n2E);
    }
}